// Round 14
// baseline (416.015 us; speedup 1.0000x reference)
//
#include <hip/hip_runtime.h>
#include <math.h>

constexpr int T = 1024;
constexpr int H = 2048;
constexpr int I = 1024;
constexpr int E = 16;
constexpr int K = 2;
constexpr int L = 4;
constexpr int R = 16;
constexpr int P = T * K;        // 2048 (token,k) pairs
constexpr int MT_MAX = 32;      // max m-tiles at BM=128
constexpr int G_CVT = T * H / (256 * 8);   // 1024 convert blocks
constexpr int G1 = MT_MAX * 64;            // 2048 gemm1 ids (BN=16)
constexpr int G2 = MT_MAX * 64;            // 2048 gemm2 ids (BN=32)

typedef __attribute__((ext_vector_type(8))) short bf16x8;
typedef __attribute__((ext_vector_type(4))) float f32x4;

__device__ inline unsigned short f2bf(float f) {
  unsigned u = __builtin_bit_cast(unsigned, f);
  u = (u + 0x7FFFu + ((u >> 16) & 1u)) >> 16;
  return (unsigned short)u;
}

__device__ inline bf16x8 pack8(f32x4 a, f32x4 b) {
  bf16x8 v;
  v[0] = (short)f2bf(a[0]); v[1] = (short)f2bf(a[1]);
  v[2] = (short)f2bf(a[2]); v[3] = (short)f2bf(a[3]);
  v[4] = (short)f2bf(b[0]); v[5] = (short)f2bf(b[1]);
  v[6] = (short)f2bf(b[2]); v[7] = (short)f2bf(b[3]);
  return v;
}

// ---------------------------------------------------------------------------
// Launch 1: cvt+zero (blocks 0..G_CVT-1) || routing (block G_CVT)
// ---------------------------------------------------------------------------
__global__ __launch_bounds__(256) void prep_kernel(
    const float* __restrict__ x, unsigned short* __restrict__ xb,
    float* __restrict__ out,
    const int* __restrict__ topk_ids, const float* __restrict__ topk_w,
    const int* __restrict__ lora_idx,
    int* __restrict__ eoff, int* __restrict__ pair_t,
    float* __restrict__ pair_w, int* __restrict__ pair_e,
    int* __restrict__ tile_e, int* __restrict__ tile_m0, int* __restrict__ ntiles) {
  const int tid = threadIdx.x;
  if (blockIdx.x < G_CVT) {
    const int i = (blockIdx.x * 256 + tid) * 8;
    f32x4 a = *reinterpret_cast<const f32x4*>(x + i);
    f32x4 b = *reinterpret_cast<const f32x4*>(x + i + 4);
    *reinterpret_cast<bf16x8*>(xb + i) = pack8(a, b);
    const f32x4 z = {0.f, 0.f, 0.f, 0.f};
    *reinterpret_cast<f32x4*>(out + i) = z;
    *reinterpret_cast<f32x4*>(out + i + 4) = z;
    return;
  }
  __shared__ int cnt2[E * L];
  __shared__ int off2[E * L + 1];
  __shared__ int cur2[E * L];
  if (tid < E * L) cnt2[tid] = 0;
  __syncthreads();
  for (int p = tid; p < P; p += 256) {
    const int e = topk_ids[p];
    int l = lora_idx[p / K];
    if (l < 0) l = 0;
    atomicAdd(&cnt2[e * L + l], 1);
  }
  __syncthreads();
  if (tid == 0) {
    off2[0] = 0;
    for (int b = 0; b < E * L; ++b) off2[b + 1] = off2[b] + cnt2[b];
    int nt = 0;
    for (int e = 0; e < E; ++e) {
      const int c = off2[(e + 1) * L] - off2[e * L];
      for (int m0 = 0; m0 < c; m0 += 128) {
        tile_e[nt] = e;
        tile_m0[nt] = m0;
        ++nt;
      }
    }
    *ntiles = nt;
  }
  __syncthreads();
  if (tid < E * L) cur2[tid] = off2[tid];
  if (tid <= E) eoff[tid] = off2[tid * L];
  __syncthreads();
  for (int p = tid; p < P; p += 256) {
    const int e = topk_ids[p];
    int l = lora_idx[p / K];
    if (l < 0) l = 0;
    const int pos = atomicAdd(&cur2[e * L + l], 1);
    pair_t[pos] = p / K;
    pair_w[pos] = topk_w[p];
    pair_e[pos] = e;
  }
}

// ---------------------------------------------------------------------------
// Launch 2: gemm1 DIRECT (no LDS, no barriers) ids 0..G1-1  || lora ids G1..
// BM=128 x BN=16 x BK=64. Fragments loaded straight from global:
//  A: lane(fr,fq) reads xb[token(wm+mi*16+fr)][kk+kb*32+fq*8 ..+8]  (L2-hot)
//  B: lane reads w1 row (i0+fr) fp32, packs to bf16 in-register
// Invalid A-rows contribute only to C-rows the store-mask drops.
// ---------------------------------------------------------------------------
__global__ __launch_bounds__(256) void gemm1_lora(
    const unsigned short* __restrict__ xb, const float* __restrict__ w1,
    const int* __restrict__ eoff, const int* __restrict__ pair_t,
    const int* __restrict__ tile_e, const int* __restrict__ tile_m0,
    const int* __restrict__ ntiles, unsigned short* __restrict__ act,
    const float* __restrict__ x, const float* __restrict__ lora_a,
    const float* __restrict__ lora_b, const int* __restrict__ lora_idx,
    const int* __restrict__ lora_ranks, const float* __restrict__ scalings,
    const int* __restrict__ pair_e, float* __restrict__ out) {
  __shared__ float a_sh[R];
  const int tid = threadIdx.x;

  if (blockIdx.x < (unsigned)G1) {
    const int bid = blockIdx.x;
    const int mt = bid >> 6;
    if (mt >= *ntiles) return;
    const int it = bid & 63;
    const int e = tile_e[mt];
    const int m0 = tile_m0[mt];
    const int beg = eoff[e];
    const int cnt = eoff[e + 1] - beg;
    const int i0 = it * 16;

    const int lane = tid & 63, wid = tid >> 6;
    const int wm = wid << 5;                 // wave rows [wm, wm+32)
    const int fr = lane & 15, fq = lane >> 4;

    const int mr0 = m0 + wm + fr;            // mi=0 row
    const int mr1 = mr0 + 16;                // mi=1 row
    const int t0 = pair_t[beg + (mr0 < cnt ? mr0 : 0)];
    const int t1 = pair_t[beg + (mr1 < cnt ? mr1 : 0)];
    const unsigned short* xr0 = xb + (size_t)t0 * H + (fq << 3);
    const unsigned short* xr1 = xb + (size_t)t1 * H + (fq << 3);
    const float* gw = w1 + ((size_t)e * (2 * I) + i0 + fr) * H + (fq << 3);
    const float* uw = gw + (size_t)I * H;

    f32x4 ag0 = {0.f, 0.f, 0.f, 0.f}, ag1 = {0.f, 0.f, 0.f, 0.f};
    f32x4 au0 = {0.f, 0.f, 0.f, 0.f}, au1 = {0.f, 0.f, 0.f, 0.f};

    for (int kk = 0; kk < H; kk += 64) {
#pragma unroll
      for (int kb = 0; kb < 2; ++kb) {
        const int off = kk + (kb << 5);
        const bf16x8 a0 = *reinterpret_cast<const bf16x8*>(xr0 + off);
        const bf16x8 a1 = *reinterpret_cast<const bf16x8*>(xr1 + off);
        const f32x4 g0 = *reinterpret_cast<const f32x4*>(gw + off);
        const f32x4 g1 = *reinterpret_cast<const f32x4*>(gw + off + 4);
        const f32x4 u0 = *reinterpret_cast<const f32x4*>(uw + off);
        const f32x4 u1 = *reinterpret_cast<const f32x4*>(uw + off + 4);
        const bf16x8 gf = pack8(g0, g1);
        const bf16x8 uf = pack8(u0, u1);
        ag0 = __builtin_amdgcn_mfma_f32_16x16x32_bf16(a0, gf, ag0, 0, 0, 0);
        au0 = __builtin_amdgcn_mfma_f32_16x16x32_bf16(a0, uf, au0, 0, 0, 0);
        ag1 = __builtin_amdgcn_mfma_f32_16x16x32_bf16(a1, gf, ag1, 0, 0, 0);
        au1 = __builtin_amdgcn_mfma_f32_16x16x32_bf16(a1, uf, au1, 0, 0, 0);
      }
    }

    // epilogue (C/D: col=lane&15 -> i; row=(lane>>4)*4+q -> m)
#pragma unroll
    for (int q = 0; q < 4; ++q) {
      const int m_0 = m0 + wm + (fq << 2) + q;
      if (m_0 < cnt) {
        const float g = ag0[q];
        const float s = g / (1.f + __expf(-g));
        act[(size_t)(beg + m_0) * I + i0 + fr] = f2bf(s * au0[q]);
      }
      const int m_1 = m_0 + 16;
      if (m_1 < cnt) {
        const float g = ag1[q];
        const float s = g / (1.f + __expf(-g));
        act[(size_t)(beg + m_1) * I + i0 + fr] = f2bf(s * au1[q]);
      }
    }
    return;
  }

  // ---- lora pair ----
  const int p = blockIdx.x - G1;
  const int t = pair_t[p];
  const int e = pair_e[p];
  const int l = lora_idx[t];
  if (l < 0) return;
  int rank = lora_ranks[l];
  if (rank < 1) rank = 1;
  const float sc = scalings[l];

  const int wave = tid >> 6, lane = tid & 63;
  const float4* xv = reinterpret_cast<const float4*>(x + (size_t)t * H);
  const float* Ab = lora_a + (size_t)(l * E + e) * R * H;
#pragma unroll
  for (int q = 0; q < 4; ++q) {
    const int r = (wave << 2) | q;
    const float4* Av = reinterpret_cast<const float4*>(Ab + (size_t)r * H);
    float s = 0.f;
#pragma unroll
    for (int it2 = 0; it2 < H / 256; ++it2) {
      const int h4 = it2 * 64 + lane;
      const float4 xx = xv[h4];
      const float4 aa = Av[h4];
      s += xx.x * aa.x + xx.y * aa.y + xx.z * aa.z + xx.w * aa.w;
    }
#pragma unroll
    for (int off = 32; off; off >>= 1) s += __shfl_xor(s, off);
    if (lane == 0) a_sh[r] = (r < rank) ? s * sc : 0.f;
  }
  __syncthreads();
  const float* Bb = lora_b + (size_t)(l * E + e) * H * R;
  for (int h = tid; h < H; h += 256) {
    const float4* Bv = reinterpret_cast<const float4*>(Bb + (size_t)h * R);
    float d = 0.f;
#pragma unroll
    for (int r4 = 0; r4 < 4; ++r4) {
      const float4 bb = Bv[r4];
      d += a_sh[r4 * 4 + 0] * bb.x + a_sh[r4 * 4 + 1] * bb.y +
           a_sh[r4 * 4 + 2] * bb.z + a_sh[r4 * 4 + 3] * bb.w;
    }
    atomicAdd(out + (size_t)t * H + h, d);
  }
}

// ---------------------------------------------------------------------------
// Launch 3: gemm2 DIRECT (no LDS, no barriers). BM=128 x BN=32 x BK=64.
// bid = mt*64 + ht; h0 = ht*32.
// ---------------------------------------------------------------------------
__global__ __launch_bounds__(256) void gemm2_mfma(
    const unsigned short* __restrict__ act, const float* __restrict__ w2,
    const int* __restrict__ eoff, const int* __restrict__ pair_t,
    const float* __restrict__ pair_w, const int* __restrict__ tile_e,
    const int* __restrict__ tile_m0, const int* __restrict__ ntiles,
    float* __restrict__ out) {
  const int bid = blockIdx.x;
  const int mt = bid >> 6;
  if (mt >= *ntiles) return;
  const int ht = bid & 63;
  const int e = tile_e[mt];
  const int m0 = tile_m0[mt];
  const int beg = eoff[e];
  const int cnt = eoff[e + 1] - beg;
  const int h0 = ht * 32;

  const int tid = threadIdx.x;
  const int lane = tid & 63, wid = tid >> 6;
  const int wm = wid << 5;
  const int fr = lane & 15, fq = lane >> 4;

  const int mr0 = m0 + wm + fr;
  const int mr1 = mr0 + 16;
  const unsigned short* ar0 =
      act + (size_t)(beg + (mr0 < cnt ? mr0 : 0)) * I + (fq << 3);
  const unsigned short* ar1 =
      act + (size_t)(beg + (mr1 < cnt ? mr1 : 0)) * I + (fq << 3);
  const float* br0 = w2 + ((size_t)e * H + h0 + fr) * I + (fq << 3);
  const float* br1 = br0 + (size_t)16 * I;

  f32x4 acc00 = {0.f, 0.f, 0.f, 0.f}, acc01 = {0.f, 0.f, 0.f, 0.f};
  f32x4 acc10 = {0.f, 0.f, 0.f, 0.f}, acc11 = {0.f, 0.f, 0.f, 0.f};

  for (int kk = 0; kk < I; kk += 64) {
#pragma unroll
    for (int kb = 0; kb < 2; ++kb) {
      const int off = kk + (kb << 5);
      const bf16x8 a0 = *reinterpret_cast<const bf16x8*>(ar0 + off);
      const bf16x8 a1 = *reinterpret_cast<const bf16x8*>(ar1 + off);
      const f32x4 b00 = *reinterpret_cast<const f32x4*>(br0 + off);
      const f32x4 b01 = *reinterpret_cast<const f32x4*>(br0 + off + 4);
      const f32x4 b10 = *reinterpret_cast<const f32x4*>(br1 + off);
      const f32x4 b11 = *reinterpret_cast<const f32x4*>(br1 + off + 4);
      const bf16x8 bf0 = pack8(b00, b01);
      const bf16x8 bf1 = pack8(b10, b11);
      acc00 = __builtin_amdgcn_mfma_f32_16x16x32_bf16(a0, bf0, acc00, 0, 0, 0);
      acc01 = __builtin_amdgcn_mfma_f32_16x16x32_bf16(a0, bf1, acc01, 0, 0, 0);
      acc10 = __builtin_amdgcn_mfma_f32_16x16x32_bf16(a1, bf0, acc10, 0, 0, 0);
      acc11 = __builtin_amdgcn_mfma_f32_16x16x32_bf16(a1, bf1, acc11, 0, 0, 0);
    }
  }

#pragma unroll
  for (int q = 0; q < 4; ++q) {
    const int m_0 = m0 + wm + (fq << 2) + q;
    if (m_0 < cnt) {
      const int tt = pair_t[beg + m_0];
      const float w = pair_w[beg + m_0];
      atomicAdd(out + (size_t)tt * H + h0 + fr, w * acc00[q]);
      atomicAdd(out + (size_t)tt * H + h0 + 16 + fr, w * acc01[q]);
    }
    const int m_1 = m_0 + 16;
    if (m_1 < cnt) {
      const int tt = pair_t[beg + m_1];
      const float w = pair_w[beg + m_1];
      atomicAdd(out + (size_t)tt * H + h0 + fr, w * acc10[q]);
      atomicAdd(out + (size_t)tt * H + h0 + 16 + fr, w * acc11[q]);
    }
  }
}

extern "C" void kernel_launch(void* const* d_in, const int* in_sizes, int n_in,
                              void* d_out, int out_size, void* d_ws, size_t ws_size,
                              hipStream_t stream) {
  const float* x          = (const float*)d_in[0];
  const int*   topk_ids   = (const int*)d_in[1];
  const float* topk_w     = (const float*)d_in[2];
  const int*   lora_idx   = (const int*)d_in[3];
  const int*   lora_ranks = (const int*)d_in[4];
  const float* scalings   = (const float*)d_in[5];
  const float* w1         = (const float*)d_in[6];
  const float* w2         = (const float*)d_in[7];
  const float* lora_a     = (const float*)d_in[8];
  const float* lora_b     = (const float*)d_in[9];
  float* out = (float*)d_out;

  char* ws = (char*)d_ws;
  int*   eoff    = (int*)(ws);             // 17 ints
  int*   ntiles  = (int*)(ws + 96);        // 1 int
  int*   tile_e  = (int*)(ws + 256);       // 32 ints
  int*   tile_m0 = (int*)(ws + 512);       // 32 ints
  int*   pair_t  = (int*)(ws + 1024);
  int*   pair_e  = (int*)(ws + 1024 + 4 * P);
  float* pair_w  = (float*)(ws + 1024 + 8 * P);
  unsigned short* xb  = (unsigned short*)(ws + 32768);                      // 4MB
  unsigned short* act = (unsigned short*)(ws + 32768 + (size_t)T * H * 2);  // 4MB

  prep_kernel<<<G_CVT + 1, 256, 0, stream>>>(x, xb, out, topk_ids, topk_w, lora_idx,
                                             eoff, pair_t, pair_w, pair_e, tile_e,
                                             tile_m0, ntiles);
  gemm1_lora<<<G1 + P, 256, 0, stream>>>(xb, w1, eoff, pair_t, tile_e, tile_m0, ntiles,
                                         act, x, lora_a, lora_b, lora_idx, lora_ranks,
                                         scalings, pair_e, out);
  gemm2_mfma<<<G2, 256, 0, stream>>>(act, w2, eoff, pair_t, pair_w, tile_e, tile_m0,
                                     ntiles, out);
}